// Round 1
// baseline (187.779 us; speedup 1.0000x reference)
//
#include <hip/hip_runtime.h>
#include <hip/hip_bf16.h>
#include <cstdint>

#define B_    8
#define S_    1024
#define DIM_  768
#define H_    12
#define HD_   64
#define SCALE_ 0.125f

typedef __attribute__((ext_vector_type(8))) __bf16 bf16x8;
typedef __attribute__((ext_vector_type(4))) float  f32x4;

// RNE float->bf16 (bit pattern as short)
__device__ __forceinline__ short f2bf(float f) {
  union { float f; uint32_t u; } a;
  a.f = f;
  uint32_t u = a.u;
  uint32_t r = (u + 0x7FFFu + ((u >> 16) & 1u)) >> 16;
  return (short)r;
}

__device__ __forceinline__ void gll16(const void* g, void* l) {
  __builtin_amdgcn_global_load_lds((const __attribute__((address_space(1))) void*)g,
                                   (__attribute__((address_space(3))) void*)l, 16, 0, 0);
}

// XOR-swizzled byte offset for [row][64] bf16 tiles (128B rows, 8x16B granules)
__device__ __forceinline__ int swz(int row, int col) {
  return row * 128 + ((((col >> 3) ^ (row & 7)) & 7) << 4) + ((col & 7) << 1);
}

// ---------------- conversion: f32 -> bf16 (vectorized) ----------------
__global__ __launch_bounds__(256) void k_cvt(const float* __restrict__ in,
                                             short* __restrict__ out, int n4) {
  int i = blockIdx.x * 256 + threadIdx.x;
  if (i >= n4) return;
  const float4 v = ((const float4*)in)[i];
  short4 o;
  o.x = f2bf(v.x); o.y = f2bf(v.y); o.z = f2bf(v.z); o.w = f2bf(v.w);
  ((short4*)out)[i] = o;
}

// ---------------- weight transpose + convert: W[k][n] -> Wt[n][k] bf16 ----------------
__global__ __launch_bounds__(256) void k_transpose(const float* __restrict__ in,
                                                   short* __restrict__ out) {
  __shared__ float tile[32][33];
  const int tx = threadIdx.x, ty = threadIdx.y;
  const int bx = blockIdx.x * 32, by = blockIdx.y * 32;
#pragma unroll
  for (int j = 0; j < 32; j += 8)
    tile[ty + j][tx] = in[(size_t)(by + ty + j) * DIM_ + bx + tx];
  __syncthreads();
#pragma unroll
  for (int j = 0; j < 32; j += 8)
    out[(size_t)(bx + ty + j) * DIM_ + by + tx] = f2bf(tile[tx][ty + j]);
}

// ---------------- GEMM: C[M][N] = A[M][768] * Bt[N][768]^T + bias ----------------
// MODE 0: out bf16, split-heads [b,h,s,d]   (A=xb,  Bt=WqT/WkT, M=8192,N=768)
// MODE 1: out bf16, V-transposed [b,h,d,s]  (A=WvT, Bt=xb,      M=768, N=8192)
// MODE 2: out f32, row-major [M][N]         (A=ow,  Bt=WpT,     M=8192,N=768)
template <int MODE>
__global__ __launch_bounds__(256) void k_gemm(const short* __restrict__ A,
                                              const short* __restrict__ Bt,
                                              const float* __restrict__ bias,
                                              void* __restrict__ out) {
  __shared__ alignas(16) char smem[32768];
  char* As = smem;
  char* Bs = smem + 16384;
  const int tid = threadIdx.x;
  const int l = tid & 63, w = tid >> 6;
  const int hi = l >> 4, lo = l & 15;
  const int wr = w >> 1, wc = w & 1;
  const int bm = blockIdx.y, bn = blockIdx.x;

  f32x4 acc[4][4];
  const f32x4 zz = {0.f, 0.f, 0.f, 0.f};
#pragma unroll
  for (int m = 0; m < 4; ++m)
#pragma unroll
    for (int n = 0; n < 4; ++n) acc[m][n] = zz;

  for (int k0 = 0; k0 < DIM_; k0 += 64) {
    __syncthreads();
#pragma unroll
    for (int i = 0; i < 4; ++i) {
      int gl = i * 256 + tid;
      int row = gl >> 3;
      int g = (gl & 7) ^ (row & 7);
      gll16(A + (size_t)(bm * 128 + row) * DIM_ + k0 + g * 8, As + gl * 16);
    }
#pragma unroll
    for (int i = 0; i < 4; ++i) {
      int gl = i * 256 + tid;
      int row = gl >> 3;
      int g = (gl & 7) ^ (row & 7);
      gll16(Bt + (size_t)(bn * 128 + row) * DIM_ + k0 + g * 8, Bs + gl * 16);
    }
    __syncthreads();
#pragma unroll
    for (int kk = 0; kk < 2; ++kk) {
      bf16x8 a[4], b[4];
#pragma unroll
      for (int m = 0; m < 4; ++m)
        a[m] = *(const bf16x8*)(As + swz(wr * 64 + m * 16 + lo, kk * 32 + hi * 8));
#pragma unroll
      for (int n = 0; n < 4; ++n)
        b[n] = *(const bf16x8*)(Bs + swz(wc * 64 + n * 16 + lo, kk * 32 + hi * 8));
#pragma unroll
      for (int m = 0; m < 4; ++m)
#pragma unroll
        for (int n = 0; n < 4; ++n)
          acc[m][n] = __builtin_amdgcn_mfma_f32_16x16x32_bf16(a[m], b[n], acc[m][n], 0, 0, 0);
    }
  }

#pragma unroll
  for (int m = 0; m < 4; ++m) {
#pragma unroll
    for (int n = 0; n < 4; ++n) {
#pragma unroll
      for (int r = 0; r < 4; ++r) {
        const int R = bm * 128 + wr * 64 + m * 16 + hi * 4 + r;
        const int C = bn * 128 + wc * 64 + n * 16 + lo;
        const float v = acc[m][n][r] + bias[MODE == 1 ? R : C];
        if (MODE == 0) {
          ((short*)out)[((size_t)((R >> 10) * H_ + (C >> 6)) * S_ + (R & 1023)) * HD_ + (C & 63)] = f2bf(v);
        } else if (MODE == 1) {
          ((short*)out)[((size_t)((C >> 10) * H_ + (R >> 6)) * HD_ + (R & 63)) * S_ + (C & 1023)] = f2bf(v);
        } else {
          ((float*)out)[(size_t)R * DIM_ + C] = v;
        }
      }
    }
  }
}

// ---------------- flash attention ----------------
// grid: B_*H_*(S_/64) blocks of 256 threads (4 waves x 16 q-rows).
// qw/kw: [bh][s][d] bf16, vtw: [bh][d][s] bf16, ow: [b][s][h*64+d] bf16.
__global__ __launch_bounds__(256) void k_attn(const short* __restrict__ qw,
                                              const short* __restrict__ kw,
                                              const short* __restrict__ vtw,
                                              short* __restrict__ ow) {
  __shared__ alignas(16) char smem[32768];
  char* Qs = smem;
  char* Ks = smem + 8192;
  char* Vs = smem + 16384;
  char* Ps = smem + 24576;
  const int tid = threadIdx.x;
  const int l = tid & 63, w = tid >> 6;
  const int hi = l >> 4, lo = l & 15;
  const int bid = blockIdx.x;
  const int qt = bid & 15;
  const int bh = bid >> 4;

  const short* qg  = qw  + (size_t)bh * 65536 + qt * 64 * 64;
  const short* kg0 = kw  + (size_t)bh * 65536;
  const short* vg0 = vtw + (size_t)bh * 65536;

  // stage Q tile (64x64, stride 64)
#pragma unroll
  for (int i = 0; i < 2; ++i) {
    int gl = i * 256 + tid;
    int row = gl >> 3;
    int g = (gl & 7) ^ (row & 7);
    gll16(qg + row * 64 + g * 8, Qs + gl * 16);
  }

  f32x4 o_acc[4];
  const f32x4 zz = {0.f, 0.f, 0.f, 0.f};
#pragma unroll
  for (int db = 0; db < 4; ++db) o_acc[db] = zz;
  float m_run[4], l_run[4];
#pragma unroll
  for (int r = 0; r < 4; ++r) { m_run[r] = -1e30f; l_run[r] = 0.f; }

  __syncthreads();
  bf16x8 aQ[2];
  aQ[0] = *(const bf16x8*)(Qs + swz(w * 16 + lo, hi * 8));
  aQ[1] = *(const bf16x8*)(Qs + swz(w * 16 + lo, 32 + hi * 8));

  for (int t = 0; t < 16; ++t) {
    __syncthreads();  // previous tile's LDS reads complete
#pragma unroll
    for (int i = 0; i < 2; ++i) {
      int gl = i * 256 + tid;
      int row = gl >> 3;
      int g = (gl & 7) ^ (row & 7);
      gll16(kg0 + (t * 64 + row) * 64 + g * 8, Ks + gl * 16);
      gll16(vg0 + row * 1024 + t * 64 + g * 8, Vs + gl * 16);
    }
    __syncthreads();

    // S = Q K^T  (per wave: 16 q-rows x 64 kv-cols)
    f32x4 sacc[4];
#pragma unroll
    for (int nb = 0; nb < 4; ++nb) sacc[nb] = zz;
#pragma unroll
    for (int kk = 0; kk < 2; ++kk) {
#pragma unroll
      for (int nb = 0; nb < 4; ++nb) {
        bf16x8 b = *(const bf16x8*)(Ks + swz(nb * 16 + lo, kk * 32 + hi * 8));
        sacc[nb] = __builtin_amdgcn_mfma_f32_16x16x32_bf16(aQ[kk], b, sacc[nb], 0, 0, 0);
      }
    }

    // online softmax (rows = hi*4 + r; 16-lane-group reductions)
    float p[4][4];
    float alpha[4];
#pragma unroll
    for (int r = 0; r < 4; ++r) {
      float mx = sacc[0][r];
#pragma unroll
      for (int nb = 1; nb < 4; ++nb) mx = fmaxf(mx, sacc[nb][r]);
      mx *= SCALE_;
#pragma unroll
      for (int mask = 1; mask < 16; mask <<= 1) mx = fmaxf(mx, __shfl_xor(mx, mask, 64));
      const float m_new = fmaxf(m_run[r], mx);
      alpha[r] = __expf(m_run[r] - m_new);
      float ps = 0.f;
#pragma unroll
      for (int nb = 0; nb < 4; ++nb) {
        const float pv = __expf(sacc[nb][r] * SCALE_ - m_new);
        p[r][nb] = pv;
        ps += pv;
      }
#pragma unroll
      for (int mask = 1; mask < 16; mask <<= 1) ps += __shfl_xor(ps, mask, 64);
      l_run[r] = l_run[r] * alpha[r] + ps;
      m_run[r] = m_new;
    }
#pragma unroll
    for (int db = 0; db < 4; ++db) {
#pragma unroll
      for (int r = 0; r < 4; ++r) o_acc[db][r] *= alpha[r];
    }

    // write P (bf16) to this wave's LDS quadrant
#pragma unroll
    for (int r = 0; r < 4; ++r)
#pragma unroll
      for (int nb = 0; nb < 4; ++nb)
        *(short*)(Ps + swz(w * 16 + hi * 4 + r, nb * 16 + lo)) = f2bf(p[r][nb]);
    asm volatile("s_waitcnt lgkmcnt(0)" ::: "memory");

    // O += P V  (B-frag from Vt[d][s])
#pragma unroll
    for (int kk = 0; kk < 2; ++kk) {
      bf16x8 ap = *(const bf16x8*)(Ps + swz(w * 16 + lo, kk * 32 + hi * 8));
#pragma unroll
      for (int db = 0; db < 4; ++db) {
        bf16x8 bv = *(const bf16x8*)(Vs + swz(db * 16 + lo, kk * 32 + hi * 8));
        o_acc[db] = __builtin_amdgcn_mfma_f32_16x16x32_bf16(ap, bv, o_acc[db], 0, 0, 0);
      }
    }
  }

  // epilogue: normalize, store to [b][s][h*64+d]
  const int b = bh / H_, h = bh % H_;
#pragma unroll
  for (int r = 0; r < 4; ++r) {
    const float inv = 1.0f / l_run[r];
    const int sg = qt * 64 + w * 16 + hi * 4 + r;
#pragma unroll
    for (int db = 0; db < 4; ++db) {
      const float o = o_acc[db][r] * inv;
      ow[((size_t)(b * S_ + sg)) * DIM_ + h * HD_ + db * 16 + lo] = f2bf(o);
    }
  }
}

extern "C" void kernel_launch(void* const* d_in, const int* in_sizes, int n_in,
                              void* d_out, int out_size, void* d_ws, size_t ws_size,
                              hipStream_t stream) {
  const float* x  = (const float*)d_in[0];
  const float* Wq = (const float*)d_in[1];
  const float* bq = (const float*)d_in[2];
  const float* Wk = (const float*)d_in[3];
  const float* bk = (const float*)d_in[4];
  const float* Wv = (const float*)d_in[5];
  const float* bv = (const float*)d_in[6];
  const float* Wp = (const float*)d_in[7];
  const float* bp = (const float*)d_in[8];

  char* ws = (char*)d_ws;
  size_t off = 0;
  auto alloc = [&](size_t bytes) {
    char* p = ws + off;
    off += (bytes + 255) & ~(size_t)255;
    return p;
  };
  short* xb  = (short*)alloc((size_t)8192 * 768 * 2);
  short* WqT = (short*)alloc((size_t)768 * 768 * 2);
  short* WkT = (short*)alloc((size_t)768 * 768 * 2);
  short* WvT = (short*)alloc((size_t)768 * 768 * 2);
  short* WpT = (short*)alloc((size_t)768 * 768 * 2);
  short* qwv = (short*)alloc((size_t)96 * 1024 * 64 * 2);
  short* kwv = (short*)alloc((size_t)96 * 1024 * 64 * 2);
  short* vtw = (short*)alloc((size_t)96 * 1024 * 64 * 2);
  short* owv = (short*)alloc((size_t)8192 * 768 * 2);

  k_cvt<<<6144, 256, 0, stream>>>(x, xb, 8192 * 768 / 4);
  dim3 tb(32, 8), tg(24, 24);
  k_transpose<<<tg, tb, 0, stream>>>(Wq, WqT);
  k_transpose<<<tg, tb, 0, stream>>>(Wk, WkT);
  k_transpose<<<tg, tb, 0, stream>>>(Wv, WvT);
  k_transpose<<<tg, tb, 0, stream>>>(Wp, WpT);

  k_gemm<0><<<dim3(6, 64), 256, 0, stream>>>(xb, WqT, bq, qwv);
  k_gemm<0><<<dim3(6, 64), 256, 0, stream>>>(xb, WkT, bk, kwv);
  k_gemm<1><<<dim3(64, 6), 256, 0, stream>>>(WvT, xb, bv, vtw);

  k_attn<<<B_ * H_ * (S_ / 64), 256, 0, stream>>>(qwv, kwv, vtw, owv);

  k_gemm<2><<<dim3(6, 64), 256, 0, stream>>>(owv, WpT, bp, d_out);
}

// Round 3
// 181.675 us; speedup vs baseline: 1.0336x; 1.0336x over previous
//
#include <hip/hip_runtime.h>
#include <hip/hip_bf16.h>
#include <cstdint>

#define B_    8
#define S_    1024
#define DIM_  768
#define H_    12
#define HD_   64
// Q is pre-scaled by SCALE*log2(e) in the Q-GEMM epilogue -> scores are in
// log2 domain; softmax uses v_exp_f32 (2^x) directly.
#define QL2S_ 0.1803368801111204f
#define THR_  8.0f

typedef __attribute__((ext_vector_type(8))) __bf16 bf16x8;
typedef __attribute__((ext_vector_type(4))) float  f32x4;

// RNE float->bf16 (bit pattern as short)
__device__ __forceinline__ short f2bf(float f) {
  union { float f; uint32_t u; } a;
  a.f = f;
  uint32_t u = a.u;
  uint32_t r = (u + 0x7FFFu + ((u >> 16) & 1u)) >> 16;
  return (short)r;
}

// 2^x via v_exp_f32 (s_nop covers the trans->VALU hazard window)
__device__ __forceinline__ float exp2a(float x) {
  float r;
  asm("v_exp_f32 %0, %1\n\ts_nop 1" : "=v"(r) : "v"(x));
  return r;
}

__device__ __forceinline__ void gll16(const void* g, void* l) {
  __builtin_amdgcn_global_load_lds((const __attribute__((address_space(1))) void*)g,
                                   (__attribute__((address_space(3))) void*)l, 16, 0, 0);
}

// XOR-swizzled byte offset for [row][64] bf16 tiles (128B rows, 8x16B granules)
__device__ __forceinline__ int swz(int row, int col) {
  return row * 128 + ((((col >> 3) ^ (row & 7)) & 7) << 4) + ((col & 7) << 1);
}

// ---------------- conversion: f32 -> bf16 (vectorized) ----------------
__global__ __launch_bounds__(256) void k_cvt(const float* __restrict__ in,
                                             short* __restrict__ out, int n4) {
  int i = blockIdx.x * 256 + threadIdx.x;
  if (i >= n4) return;
  const float4 v = ((const float4*)in)[i];
  short4 o;
  o.x = f2bf(v.x); o.y = f2bf(v.y); o.z = f2bf(v.z); o.w = f2bf(v.w);
  ((short4*)out)[i] = o;
}

// ---------------- weight transpose + convert: W[k][n] -> Wt[n][k] bf16 ----------------
__global__ __launch_bounds__(256) void k_transpose(const float* __restrict__ in,
                                                   short* __restrict__ out) {
  __shared__ float tile[32][33];
  const int tx = threadIdx.x, ty = threadIdx.y;
  const int bx = blockIdx.x * 32, by = blockIdx.y * 32;
#pragma unroll
  for (int j = 0; j < 32; j += 8)
    tile[ty + j][tx] = in[(size_t)(by + ty + j) * DIM_ + bx + tx];
  __syncthreads();
#pragma unroll
  for (int j = 0; j < 32; j += 8)
    out[(size_t)(bx + ty + j) * DIM_ + by + tx] = f2bf(tile[tx][ty + j]);
}

// ---------------- GEMM body: C[M][N] = A[M][768] * Bt[N][768]^T + bias ----------------
// MODE 0: out bf16, split-heads [b,h,s,d]   (QS: scale by QL2S_ for Q)
// MODE 1: out bf16, V-transposed [b,h,d,s]
// MODE 2: out f32, row-major [M][N]
template <int MODE, bool QS>
__device__ __forceinline__ void gemm_body(char* smem,
                                          const short* __restrict__ A,
                                          const short* __restrict__ Bt,
                                          const float* __restrict__ bias,
                                          void* __restrict__ out,
                                          int bm, int bn) {
  char* As = smem;
  char* Bs = smem + 16384;
  const int tid = threadIdx.x;
  const int l = tid & 63, w = tid >> 6;
  const int hi = l >> 4, lo = l & 15;
  const int wr = w >> 1, wc = w & 1;

  f32x4 acc[4][4];
  const f32x4 zz = {0.f, 0.f, 0.f, 0.f};
#pragma unroll
  for (int m = 0; m < 4; ++m)
#pragma unroll
    for (int n = 0; n < 4; ++n) acc[m][n] = zz;

  for (int k0 = 0; k0 < DIM_; k0 += 64) {
    __syncthreads();
#pragma unroll
    for (int i = 0; i < 4; ++i) {
      int gl = i * 256 + tid;
      int row = gl >> 3;
      int g = (gl & 7) ^ (row & 7);
      gll16(A + (size_t)(bm * 128 + row) * DIM_ + k0 + g * 8, As + gl * 16);
    }
#pragma unroll
    for (int i = 0; i < 4; ++i) {
      int gl = i * 256 + tid;
      int row = gl >> 3;
      int g = (gl & 7) ^ (row & 7);
      gll16(Bt + (size_t)(bn * 128 + row) * DIM_ + k0 + g * 8, Bs + gl * 16);
    }
    __syncthreads();
#pragma unroll
    for (int kk = 0; kk < 2; ++kk) {
      bf16x8 a[4], b[4];
#pragma unroll
      for (int m = 0; m < 4; ++m)
        a[m] = *(const bf16x8*)(As + swz(wr * 64 + m * 16 + lo, kk * 32 + hi * 8));
#pragma unroll
      for (int n = 0; n < 4; ++n)
        b[n] = *(const bf16x8*)(Bs + swz(wc * 64 + n * 16 + lo, kk * 32 + hi * 8));
#pragma unroll
      for (int m = 0; m < 4; ++m)
#pragma unroll
        for (int n = 0; n < 4; ++n)
          acc[m][n] = __builtin_amdgcn_mfma_f32_16x16x32_bf16(a[m], b[n], acc[m][n], 0, 0, 0);
    }
  }

#pragma unroll
  for (int m = 0; m < 4; ++m) {
#pragma unroll
    for (int n = 0; n < 4; ++n) {
#pragma unroll
      for (int r = 0; r < 4; ++r) {
        const int R = bm * 128 + wr * 64 + m * 16 + hi * 4 + r;
        const int C = bn * 128 + wc * 64 + n * 16 + lo;
        float v = acc[m][n][r] + bias[MODE == 1 ? R : C];
        if (QS) v *= QL2S_;
        if (MODE == 0) {
          ((short*)out)[((size_t)((R >> 10) * H_ + (C >> 6)) * S_ + (R & 1023)) * HD_ + (C & 63)] = f2bf(v);
        } else if (MODE == 1) {
          ((short*)out)[((size_t)((C >> 10) * H_ + (R >> 6)) * HD_ + (R & 63)) * S_ + (C & 1023)] = f2bf(v);
        } else {
          ((float*)out)[(size_t)R * DIM_ + C] = v;
        }
      }
    }
  }
}

// fused QKV: grid (64, 6, 3)
__global__ __launch_bounds__(256) void k_gemm_qkv(const short* __restrict__ xb,
                                                  const short* __restrict__ WqT,
                                                  const short* __restrict__ WkT,
                                                  const short* __restrict__ WvT,
                                                  const float* __restrict__ bq,
                                                  const float* __restrict__ bk,
                                                  const float* __restrict__ bv,
                                                  short* qo, short* ko, short* vo) {
  __shared__ alignas(16) char smem[32768];
  if (blockIdx.z == 0)
    gemm_body<0, true>(smem, xb, WqT, bq, qo, blockIdx.x, blockIdx.y);
  else if (blockIdx.z == 1)
    gemm_body<0, false>(smem, xb, WkT, bk, ko, blockIdx.x, blockIdx.y);
  else
    gemm_body<1, false>(smem, WvT, xb, bv, vo, blockIdx.y, blockIdx.x);
}

// output projection: grid (6, 64)
__global__ __launch_bounds__(256) void k_gemm_proj(const short* __restrict__ A,
                                                   const short* __restrict__ Bt,
                                                   const float* __restrict__ bias,
                                                   float* out) {
  __shared__ alignas(16) char smem[32768];
  gemm_body<2, false>(smem, A, Bt, bias, out, blockIdx.y, blockIdx.x);
}

// ---------------- flash attention, barrier-free ----------------
// grid: B_*H_*(S_/128) = 768 blocks of 256 threads (4 waves x 32 q-rows).
// All MFMA operands (Q, K, Vt) are loaded as 16B-contiguous global reads
// (L2/L3-resident); only P round-trips through per-wave-private LDS.
__global__ __launch_bounds__(256, 3) void k_attn(const short* __restrict__ qw,
                                                 const short* __restrict__ kw,
                                                 const short* __restrict__ vtw,
                                                 short* __restrict__ ow) {
  __shared__ alignas(16) char Ps[16384];  // [128 q][64 kv] bf16, swizzled
  const int tid = threadIdx.x;
  const int l = tid & 63, w = tid >> 6;
  const int hi = l >> 4, lo = l & 15;
  const int qt = blockIdx.x & 7;
  const int bh = blockIdx.x >> 3;

  const short* qg = qw  + (size_t)bh * (S_ * HD_) + (qt * 128) * HD_;
  const short* kg = kw  + (size_t)bh * (S_ * HD_);
  const short* vg = vtw + (size_t)bh * (S_ * HD_);

  // Q fragments direct from global: A-frag row = lane&15, k = (lane>>4)*8+j
  bf16x8 aQ[2][2];
#pragma unroll
  for (int m = 0; m < 2; ++m)
#pragma unroll
    for (int kk = 0; kk < 2; ++kk)
      aQ[m][kk] = *(const bf16x8*)(qg + (w * 32 + m * 16 + lo) * HD_ + kk * 32 + hi * 8);

  f32x4 o_acc[2][4];
  const f32x4 zz = {0.f, 0.f, 0.f, 0.f};
#pragma unroll
  for (int m = 0; m < 2; ++m)
#pragma unroll
    for (int db = 0; db < 4; ++db) o_acc[m][db] = zz;
  float m_run[2][4], l_run[2][4];
#pragma unroll
  for (int m = 0; m < 2; ++m)
#pragma unroll
    for (int r = 0; r < 4; ++r) { m_run[m][r] = -1e30f; l_run[m][r] = 0.f; }

  for (int t = 0; t < 16; ++t) {
    // ---- QK^T (K B-frags direct from global) ----
    f32x4 sacc[2][4];
#pragma unroll
    for (int m = 0; m < 2; ++m)
#pragma unroll
      for (int nb = 0; nb < 4; ++nb) sacc[m][nb] = zz;
#pragma unroll
    for (int kk = 0; kk < 2; ++kk) {
#pragma unroll
      for (int nb = 0; nb < 4; ++nb) {
        const bf16x8 bK = *(const bf16x8*)(kg + (t * 64 + nb * 16 + lo) * HD_ + kk * 32 + hi * 8);
#pragma unroll
        for (int m = 0; m < 2; ++m)
          sacc[m][nb] = __builtin_amdgcn_mfma_f32_16x16x32_bf16(aQ[m][kk], bK, sacc[m][nb], 0, 0, 0);
      }
    }

    // ---- online softmax (log2 domain; rows hi*4+r, cols across lo lanes) ----
    float tmax[2][4];
#pragma unroll
    for (int m = 0; m < 2; ++m) {
#pragma unroll
      for (int r = 0; r < 4; ++r) {
        float mx = fmaxf(fmaxf(sacc[m][0][r], sacc[m][1][r]),
                         fmaxf(sacc[m][2][r], sacc[m][3][r]));
#pragma unroll
        for (int mask = 1; mask < 16; mask <<= 1) mx = fmaxf(mx, __shfl_xor(mx, mask, 64));
        tmax[m][r] = mx;
      }
    }
    bool c = true;
#pragma unroll
    for (int m = 0; m < 2; ++m)
#pragma unroll
      for (int r = 0; r < 4; ++r) c = c && (tmax[m][r] <= m_run[m][r] + THR_);
    if (!__all(c)) {  // rescale (rare after the first tile: defer-max)
#pragma unroll
      for (int m = 0; m < 2; ++m) {
#pragma unroll
        for (int r = 0; r < 4; ++r) {
          const float mn = fmaxf(m_run[m][r], tmax[m][r]);
          const float al = exp2a(m_run[m][r] - mn);
          l_run[m][r] *= al;
          m_run[m][r] = mn;
#pragma unroll
          for (int db = 0; db < 4; ++db) o_acc[m][db][r] *= al;
        }
      }
    }
#pragma unroll
    for (int m = 0; m < 2; ++m) {
#pragma unroll
      for (int r = 0; r < 4; ++r) {
        float ps = 0.f;
#pragma unroll
        for (int nb = 0; nb < 4; ++nb) {
          const float p = exp2a(sacc[m][nb][r] - m_run[m][r]);
          ps += p;
          *(short*)(Ps + swz(w * 32 + m * 16 + hi * 4 + r, nb * 16 + lo)) = f2bf(p);
        }
#pragma unroll
        for (int mask = 1; mask < 16; mask <<= 1) ps += __shfl_xor(ps, mask, 64);
        l_run[m][r] += ps;
      }
    }
    asm volatile("s_waitcnt lgkmcnt(0)" ::: "memory");
    __builtin_amdgcn_sched_barrier(0);

    // ---- O += P V (P from own LDS quadrant, V B-frags direct from global) ----
#pragma unroll
    for (int kk = 0; kk < 2; ++kk) {
      bf16x8 aP[2];
#pragma unroll
      for (int m = 0; m < 2; ++m)
        aP[m] = *(const bf16x8*)(Ps + swz(w * 32 + m * 16 + lo, kk * 32 + hi * 8));
#pragma unroll
      for (int db = 0; db < 4; ++db) {
        const bf16x8 bV = *(const bf16x8*)(vg + (db * 16 + lo) * S_ + t * 64 + kk * 32 + hi * 8);
#pragma unroll
        for (int m = 0; m < 2; ++m)
          o_acc[m][db] = __builtin_amdgcn_mfma_f32_16x16x32_bf16(aP[m], bV, o_acc[m][db], 0, 0, 0);
      }
    }
  }

  // epilogue: normalize, store to [b][s][h*64+d]
  const int b = bh / H_, h = bh % H_;
#pragma unroll
  for (int m = 0; m < 2; ++m) {
#pragma unroll
    for (int r = 0; r < 4; ++r) {
      const float inv = 1.0f / l_run[m][r];
      const int sg = qt * 128 + w * 32 + m * 16 + hi * 4 + r;
#pragma unroll
      for (int db = 0; db < 4; ++db)
        ow[((size_t)(b * S_ + sg)) * DIM_ + h * HD_ + db * 16 + lo] = f2bf(o_acc[m][db][r] * inv);
    }
  }
}

extern "C" void kernel_launch(void* const* d_in, const int* in_sizes, int n_in,
                              void* d_out, int out_size, void* d_ws, size_t ws_size,
                              hipStream_t stream) {
  const float* x  = (const float*)d_in[0];
  const float* Wq = (const float*)d_in[1];
  const float* bq = (const float*)d_in[2];
  const float* Wk = (const float*)d_in[3];
  const float* bk = (const float*)d_in[4];
  const float* Wv = (const float*)d_in[5];
  const float* bv = (const float*)d_in[6];
  const float* Wp = (const float*)d_in[7];
  const float* bp = (const float*)d_in[8];

  char* ws = (char*)d_ws;
  size_t off = 0;
  auto alloc = [&](size_t bytes) {
    char* p = ws + off;
    off += (bytes + 255) & ~(size_t)255;
    return p;
  };
  short* xb  = (short*)alloc((size_t)8192 * 768 * 2);
  short* WqT = (short*)alloc((size_t)768 * 768 * 2);
  short* WkT = (short*)alloc((size_t)768 * 768 * 2);
  short* WvT = (short*)alloc((size_t)768 * 768 * 2);
  short* WpT = (short*)alloc((size_t)768 * 768 * 2);
  short* qwv = (short*)alloc((size_t)96 * 1024 * 64 * 2);
  short* kwv = (short*)alloc((size_t)96 * 1024 * 64 * 2);
  short* vtw = (short*)alloc((size_t)96 * 1024 * 64 * 2);
  short* owv = (short*)alloc((size_t)8192 * 768 * 2);

  k_cvt<<<6144, 256, 0, stream>>>(x, xb, 8192 * 768 / 4);
  dim3 tb(32, 8), tg(24, 24);
  k_transpose<<<tg, tb, 0, stream>>>(Wq, WqT);
  k_transpose<<<tg, tb, 0, stream>>>(Wk, WkT);
  k_transpose<<<tg, tb, 0, stream>>>(Wv, WvT);
  k_transpose<<<tg, tb, 0, stream>>>(Wp, WpT);

  k_gemm_qkv<<<dim3(64, 6, 3), 256, 0, stream>>>(xb, WqT, WkT, WvT, bq, bk, bv, qwv, kwv, vtw);

  k_attn<<<B_ * H_ * (S_ / 128), 256, 0, stream>>>(qwv, kwv, vtw, owv);

  k_gemm_proj<<<dim3(6, 64), 256, 0, stream>>>(owv, WpT, bp, (float*)d_out);
}